// Round 2
// baseline (245.738 us; speedup 1.0000x reference)
//
#include <hip/hip_runtime.h>
#include <hip/hip_bf16.h>
#include <math.h>

#define GG 8192      // graphs = B*T
#define NODESN 23
#define KK 8
#define DIN 16
#define HH 128
#define RHH 128
#define EPG (NODESN*KK)   // 184 edges per graph
#define TTT 128
#define BBB 64

// ---------------------------------------------------------------------------
// DPP cross-lane add (VALU pipe -- NOT the DS pipe, unlike __shfl_xor).
// ---------------------------------------------------------------------------
template<int CTRL>
static __device__ __forceinline__ float dpp_add(float v) {
    int x = __builtin_amdgcn_update_dpp(0, __float_as_int(v), CTRL, 0xF, 0xF, true);
    return v + __int_as_float(x);
}
#define DPP_XOR1 0xB1   // quad_perm [1,0,3,2]
#define DPP_XOR2 0x4E   // quad_perm [2,3,0,1]
#define DPP_MIR7 0x141  // row_half_mirror: lane l <-> l^7 within 8-lane half-row
#define DPP_SHL4 0x104  // row_shl:4 (lane l <- lane l+4)

// ---------------------------------------------------------------------------
// Kernel 1: per-graph GCN up to hsum (layer-1 + neighborhood aggregation).
// ---------------------------------------------------------------------------
__global__ __launch_bounds__(256) void gcn_hsum(
    const float* __restrict__ x, const int* __restrict__ esrc,
    const int* __restrict__ runner,
    const float* __restrict__ W1, const float* __restrict__ b1,
    float* __restrict__ hsum_g)
{
    __shared__ float xs[NODESN * DIN];
    __shared__ int   srcs[EPG];
    __shared__ float t1[NODESN * HH];
    __shared__ float red[256];

    const int g   = blockIdx.x;
    const int tid = threadIdx.x;
    const int j   = tid & 127;
    const int nh  = tid >> 7;

    for (int i = tid; i < NODESN * DIN; i += 256) xs[i] = x[g * NODESN * DIN + i];
    for (int i = tid; i < EPG; i += 256)          srcs[i] = esrc[g * EPG + i] - g * NODESN;

    float w[DIN];
    #pragma unroll
    for (int k = 0; k < DIN; k++) w[k] = W1[k * HH + j];
    const float b1j = b1[j];
    __syncthreads();

    const int n0 = nh * 12;
    const int n1 = nh ? NODESN : 12;
    for (int n = n0; n < n1; n++) {
        float acc = 0.f;
        #pragma unroll
        for (int k = 0; k < DIN; k += 4) {
            float4 xv = *(const float4*)&xs[n * DIN + k];
            acc = fmaf(xv.x, w[k], fmaf(xv.y, w[k+1], fmaf(xv.z, w[k+2], fmaf(xv.w, w[k+3], acc))));
        }
        t1[n * HH + j] = acc;
    }
    __syncthreads();

    const int r = runner[g];
    float part = 0.f;
    for (int slot = nh; slot < 9; slot += 2) {
        int node = (slot < 8) ? srcs[r * KK + slot] : r;
        float acc = t1[node * HH + j];
        #pragma unroll
        for (int k = 0; k < KK; k++) acc += t1[srcs[node * KK + k] * HH + j];
        part += fmaxf(acc * (1.f / 9.f) + b1j, 0.f);
    }
    red[tid] = part;
    __syncthreads();
    if (tid < HH) hsum_g[(size_t)g * HH + tid] = red[tid] + red[tid + 128];
}

// ---------------------------------------------------------------------------
// Kernel 2: seq = relu((1/9) * hsum @ W2 + b2), 16 graphs per block.
// ---------------------------------------------------------------------------
__global__ __launch_bounds__(256) void seq_kernel(
    const float* __restrict__ hsum_g, const float* __restrict__ W2,
    const float* __restrict__ b2, float* __restrict__ seq)
{
    __shared__ float hs[16 * HH];
    const int tid = threadIdx.x;
    const int j = tid & 127, mh = tid >> 7;
    const size_t base = (size_t)blockIdx.x * 16 * HH;

    for (int v = tid; v < 16 * HH / 4; v += 256)
        ((float4*)hs)[v] = ((const float4*)(hsum_g + base))[v];
    __syncthreads();

    float acc[8];
    #pragma unroll
    for (int m = 0; m < 8; m++) acc[m] = 0.f;
    const float* hrow = hs + mh * 8 * HH;
    for (int k = 0; k < HH; k += 4) {
        float w0  = W2[(k+0)*HH + j];
        float w1  = W2[(k+1)*HH + j];
        float w2v = W2[(k+2)*HH + j];
        float w3  = W2[(k+3)*HH + j];
        #pragma unroll
        for (int m = 0; m < 8; m++) {
            float4 hv = *(const float4*)&hrow[m * HH + k];
            acc[m] = fmaf(hv.x, w0, fmaf(hv.y, w1, fmaf(hv.z, w2v, fmaf(hv.w, w3, acc[m]))));
        }
    }
    const float bj = b2[j];
    #pragma unroll
    for (int m = 0; m < 8; m++)
        seq[base + (size_t)(mh * 8 + m) * HH + j] = fmaxf(acc[m] * (1.f/9.f) + bj, 0.f);
}

// ---------------------------------------------------------------------------
// Kernel 3: transpose W_ih [384,128] -> WT [128,384]
// ---------------------------------------------------------------------------
__global__ void transpose_wih(const float* __restrict__ W, float* __restrict__ WT)
{
    int idx = blockIdx.x * 256 + threadIdx.x;
    if (idx < 3 * RHH * RHH) {
        int jj = idx / RHH, kk = idx - jj * RHH;
        WT[kk * (3 * RHH) + jj] = W[idx];
    }
}

// ---------------------------------------------------------------------------
// Kernel 4: xg = seq @ W_ih^T + b_ih   [8192,128]@[128,384]
// ---------------------------------------------------------------------------
__global__ __launch_bounds__(384) void xg_kernel(
    const float* __restrict__ seq, const float* __restrict__ WT,
    const float* __restrict__ b_ih, float* __restrict__ xg)
{
    const int tid = threadIdx.x;
    const int m0 = blockIdx.x * 8;
    const float* srow = seq + (size_t)m0 * RHH;
    float acc[8];
    const float bv = b_ih[tid];
    #pragma unroll
    for (int mi = 0; mi < 8; mi++) acc[mi] = bv;
    for (int k = 0; k < RHH; k += 4) {
        float w0 = WT[(k+0)*384 + tid];
        float w1 = WT[(k+1)*384 + tid];
        float w2 = WT[(k+2)*384 + tid];
        float w3 = WT[(k+3)*384 + tid];
        #pragma unroll
        for (int mi = 0; mi < 8; mi++) {
            float4 sv = *(const float4*)(srow + mi * RHH + k);
            acc[mi] = fmaf(sv.x, w0, fmaf(sv.y, w1, fmaf(sv.z, w2, fmaf(sv.w, w3, acc[mi]))));
        }
    }
    #pragma unroll
    for (int mi = 0; mi < 8; mi++)
        xg[(size_t)(m0 + mi) * 384 + tid] = acc[mi];
}

// ---------------------------------------------------------------------------
// Kernel 5: GRU. 512 threads (8 waves) per batch element.
//
// R9 re-tiling (DS-pipe cut): thread (i0,kq) with kq = tid&7 (k-eighth),
// i0 = tid>>3 owns TWO hidden units (2*i0, 2*i0+1) x 3 gates over a 16-float
// k-slice [16kq, 16kq+16).  Per-step LDS h-broadcast traffic scales as 1/u
// (u = gate-outputs per thread); u: 3 -> 6 halves the h-read DS instrs
// (8 -> 4 ds_read_b128/thread) and each hv float4 now feeds 6 accumulators
// instead of 3.  k-reduction is an 8-lane pure-VALU DPP butterfly:
// xor1 + xor2 (quad_perm) + row_half_mirror (lane^7; valid because after the
// two quad stages every quad lane holds the full quad sum).  Gates are
// lane-specialized: lanes kq<4 compute unit 2*i0, kq>=4 unit 2*i0+1 (one
// v_cndmask per reduced sum), so gate VALU does not double; lanes kq==0 and
// kq==4 publish.  Phase rotation p=(m+kq)&3 keeps the 8 unique h addresses
// per wave-read at 2-way-max bank aliasing (2-way is free).  The per-step
// xgbuf read is software-pipelined across the barrier (xgbuf is chunk-stable).
// Per step per CU DS budget: 32 h-reads (b128) + 8 xg reads + 1 h-write
// vs R8's ~73.  84 KB LDS -> 1 block/CU.
// ---------------------------------------------------------------------------
#define CHUNK 32
#define XGB_FLOATS (CHUNK * HH * 4)      // 16384 floats = 64 KB

__global__ __launch_bounds__(512)
__attribute__((amdgpu_waves_per_eu(2, 2)))
void gru_kernel(
    const float* __restrict__ xg, const float* __restrict__ W_hh,
    const float* __restrict__ b_hh, const float* __restrict__ Wp,
    const float* __restrict__ bp, float* __restrict__ out)
{
    __shared__ float xgbuf[XGB_FLOATS];          // [tl][i][{xr,xz,xn,pad}]
    __shared__ float houtb[(CHUNK + 2) * HH];    // rows 1..32 = h(t); row 32 also carry
    __shared__ float wps[2 * RHH + 2];           // Wp + bp
    // total 83.9 KB -> exactly 1 block/CU

    const int b   = blockIdx.x;
    const int tid = threadIdx.x;
    const int kq  = tid & 7;       // k-eighth, lane bits 0-2 (DPP butterfly domain)
    const int i0  = tid >> 3;      // unit pair 0..63
    const int uhf = kq >> 2;       // which unit of the pair this lane's gates handle
    const int u   = 2 * i0 + uhf;  // this lane's gate unit

    // ---- preload W_hh slices: rows {2i0, 2i0+1} x {r,z,n}, cols [16kq,16kq+16),
    // phase-rotated p=(m+kq)&3 (matches the h-read rotation below).
    float4 wr0[4], wz0[4], wn0[4], wr1[4], wz1[4], wn1[4];
    int hof[4];
    {
        const float* w0 = W_hh + (size_t)(2 * i0) * RHH + kq * 16;
        #pragma unroll
        for (int m = 0; m < 4; m++) {
            const int off = 4 * ((m + kq) & 3);
            hof[m] = kq * 16 + off;
            wr0[m] = *(const float4*)(w0 + off);
            wz0[m] = *(const float4*)(w0 + RHH * RHH + off);
            wn0[m] = *(const float4*)(w0 + 2 * RHH * RHH + off);
            wr1[m] = *(const float4*)(w0 + RHH + off);
            wz1[m] = *(const float4*)(w0 + RHH * RHH + RHH + off);
            wn1[m] = *(const float4*)(w0 + 2 * RHH * RHH + RHH + off);
        }
    }
    const float bhr = b_hh[u];
    const float bhz = b_hh[RHH + u];
    const float bhn = b_hh[2 * RHH + u];

    if (tid < 2 * RHH) wps[tid] = Wp[tid];
    if (tid < 2)       wps[2 * RHH + tid] = bp[tid];
    if (tid < HH)      houtb[CHUNK * HH + tid] = 0.f;   // carry row = h(-1) = 0
    float hprev = 0.f;

    const float* xbase = xg + (size_t)b * TTT * 3 * RHH;
    float* outb = out + (size_t)b * TTT * 2;

    for (int c = 0; c < TTT / CHUNK; c++) {
        // ---- refill xgbuf for chunk c, repacking to [tl][i][{r,z,n,pad}]
        #pragma unroll
        for (int k2 = 0; k2 < 8; k2++) {
            int slot = tid + (k2 << 9);          // 0..4095
            int tl = slot >> 7, ii = slot & 127;
            const float* gsrc = xbase + (size_t)(c * CHUNK + tl) * 384 + ii;
            float4 v;
            v.x = gsrc[0]; v.y = gsrc[128]; v.z = gsrc[256]; v.w = 0.f;
            *(float4*)&xgbuf[slot << 2] = v;
        }
        // ---- project previous chunk: out = houtb[1..32] @ Wp + bp
        if (c > 0) {
            const int s  = tid & 7;              // 16-float k-slice
            const int cc = (tid >> 3) & 1;
            const int tl = tid >> 4;             // 0..31
            const float* hr = &houtb[(tl + 1) * HH + s * 16];
            float acc = 0.f;
            #pragma unroll
            for (int m = 0; m < 16; m += 4) {
                float4 hv = *(const float4*)(hr + m);
                int k = s * 16 + m;
                acc = fmaf(hv.x, wps[(k+0)*2 + cc],
                      fmaf(hv.y, wps[(k+1)*2 + cc],
                      fmaf(hv.z, wps[(k+2)*2 + cc],
                      fmaf(hv.w, wps[(k+3)*2 + cc], acc))));
            }
            acc = dpp_add<DPP_XOR1>(acc);
            acc = dpp_add<DPP_XOR2>(acc);
            acc = dpp_add<DPP_SHL4>(acc);        // valid in lanes s<4
            if (s == 0)
                outb[((c - 1) * CHUNK + tl) * 2 + cc] = acc + wps[2 * RHH + cc];
        }
        __syncthreads();

        // ---- 32 steps; per step per thread: 4 ds_read_b128 (h) + 1 (xg,
        // pipelined from previous iteration) + 1 masked write
        float4 xgv = *(const float4*)&xgbuf[u << 2];   // tl=0 row
        for (int tl = 0; tl < CHUNK; tl++) {
            const float* hrow = &houtb[(tl == 0 ? CHUNK : tl) * HH];
            // prefetch next step's xg row (xgbuf is stable within the chunk,
            // so this is legal across the step barrier -> off the critical path)
            float4 xgn = xgv;
            if (tl + 1 < CHUNK)
                xgn = *(const float4*)&xgbuf[((tl + 1) * HH + u) << 2];

            float ar0 = 0.f, az0 = 0.f, an0 = 0.f;
            float ar1 = 0.f, az1 = 0.f, an1 = 0.f;
            #pragma unroll
            for (int m = 0; m < 4; m++) {
                float4 hv = *(const float4*)(hrow + hof[m]);
                ar0 = fmaf(hv.x, wr0[m].x, fmaf(hv.y, wr0[m].y, fmaf(hv.z, wr0[m].z, fmaf(hv.w, wr0[m].w, ar0))));
                az0 = fmaf(hv.x, wz0[m].x, fmaf(hv.y, wz0[m].y, fmaf(hv.z, wz0[m].z, fmaf(hv.w, wz0[m].w, az0))));
                an0 = fmaf(hv.x, wn0[m].x, fmaf(hv.y, wn0[m].y, fmaf(hv.z, wn0[m].z, fmaf(hv.w, wn0[m].w, an0))));
                ar1 = fmaf(hv.x, wr1[m].x, fmaf(hv.y, wr1[m].y, fmaf(hv.z, wr1[m].z, fmaf(hv.w, wr1[m].w, ar1))));
                az1 = fmaf(hv.x, wz1[m].x, fmaf(hv.y, wz1[m].y, fmaf(hv.z, wz1[m].z, fmaf(hv.w, wz1[m].w, az1))));
                an1 = fmaf(hv.x, wn1[m].x, fmaf(hv.y, wn1[m].y, fmaf(hv.z, wn1[m].z, fmaf(hv.w, wn1[m].w, an1))));
            }
            // 8-lane butterfly: xor1, xor2 (quad sums in all quad lanes),
            // then half-mirror (l^7) pulls the other quad's sum -> full 8-sum
            ar0 = dpp_add<DPP_XOR1>(ar0); ar0 = dpp_add<DPP_XOR2>(ar0); ar0 = dpp_add<DPP_MIR7>(ar0);
            az0 = dpp_add<DPP_XOR1>(az0); az0 = dpp_add<DPP_XOR2>(az0); az0 = dpp_add<DPP_MIR7>(az0);
            an0 = dpp_add<DPP_XOR1>(an0); an0 = dpp_add<DPP_XOR2>(an0); an0 = dpp_add<DPP_MIR7>(an0);
            ar1 = dpp_add<DPP_XOR1>(ar1); ar1 = dpp_add<DPP_XOR2>(ar1); ar1 = dpp_add<DPP_MIR7>(ar1);
            az1 = dpp_add<DPP_XOR1>(az1); az1 = dpp_add<DPP_XOR2>(az1); az1 = dpp_add<DPP_MIR7>(az1);
            an1 = dpp_add<DPP_XOR1>(an1); an1 = dpp_add<DPP_XOR2>(an1); an1 = dpp_add<DPP_MIR7>(an1);

            // lane-specialized gates: lower half-group -> unit 2i0, upper -> 2i0+1
            float ar = uhf ? ar1 : ar0;
            float az = uhf ? az1 : az0;
            float an = uhf ? an1 : an0;

            float sr = xgv.x + ar + bhr;
            float sz = xgv.y + az + bhz;
            float rg = 1.f / (1.f + __expf(-sr));
            float zg = 1.f / (1.f + __expf(-sz));
            float tv = fmaf(rg, an + bhn, xgv.z);
            tv = fminf(fmaxf(tv, -15.f), 15.f);
            float e2 = __expf(-2.f * tv);
            float ng = (1.f - e2) / (1.f + e2);
            hprev = fmaf(zg, hprev, (1.f - zg) * ng);
            if ((kq & 3) == 0) houtb[(tl + 1) * HH + u] = hprev;  // kq=0 -> 2i0, kq=4 -> 2i0+1
            xgv = xgn;
            __syncthreads();
        }
    }

    // ---- project the last chunk
    {
        const int s  = tid & 7;
        const int cc = (tid >> 3) & 1;
        const int tl = tid >> 4;
        const float* hr = &houtb[(tl + 1) * HH + s * 16];
        float acc = 0.f;
        #pragma unroll
        for (int m = 0; m < 16; m += 4) {
            float4 hv = *(const float4*)(hr + m);
            int k = s * 16 + m;
            acc = fmaf(hv.x, wps[(k+0)*2 + cc],
                  fmaf(hv.y, wps[(k+1)*2 + cc],
                  fmaf(hv.z, wps[(k+2)*2 + cc],
                  fmaf(hv.w, wps[(k+3)*2 + cc], acc))));
        }
        acc = dpp_add<DPP_XOR1>(acc);
        acc = dpp_add<DPP_XOR2>(acc);
        acc = dpp_add<DPP_SHL4>(acc);
        if (s == 0)
            outb[((TTT / CHUNK - 1) * CHUNK + tl) * 2 + cc] = acc + wps[2 * RHH + cc];
    }
}

extern "C" void kernel_launch(void* const* d_in, const int* in_sizes, int n_in,
                              void* d_out, int out_size, void* d_ws, size_t ws_size,
                              hipStream_t stream)
{
    const float* x      = (const float*)d_in[0];
    const int*   eidx   = (const int*)d_in[1];
    const int*   runner = (const int*)d_in[2];
    const float* W1     = (const float*)d_in[3];
    const float* b1     = (const float*)d_in[4];
    const float* W2     = (const float*)d_in[5];
    const float* b2     = (const float*)d_in[6];
    const float* W_ih   = (const float*)d_in[7];
    const float* W_hh   = (const float*)d_in[8];
    const float* b_ih   = (const float*)d_in[9];
    const float* b_hh   = (const float*)d_in[10];
    const float* Wp     = (const float*)d_in[11];
    const float* bp     = (const float*)d_in[12];
    float* out = (float*)d_out;

    float* seq    = (float*)d_ws;                    // 8192*128   [0, 4 MB)
    float* xg     = seq + (size_t)GG * HH;           // 8192*384   [4, 16.6 MB)
    float* WT     = xg + (size_t)GG * 3 * RHH;       // 128*384
    float* hsum_g = xg;   // alias: dead before xg_kernel writes xg

    transpose_wih<<<192, 256, 0, stream>>>(W_ih, WT);
    gcn_hsum<<<GG, 256, 0, stream>>>(x, eidx, runner, W1, b1, hsum_g);
    seq_kernel<<<GG / 16, 256, 0, stream>>>(hsum_g, W2, b2, seq);
    xg_kernel<<<GG / 8, 384, 0, stream>>>(seq, WT, b_ih, xg);
    gru_kernel<<<BBB, 512, 0, stream>>>(xg, W_hh, b_hh, Wp, bp, out);
}